// Round 3
// baseline (233.407 us; speedup 1.0000x reference)
//
#include <hip/hip_runtime.h>
#include <stdint.h>

#define NS 4096
#define DIM 2048
#define MARGINF 0.3f

typedef __bf16 bf16x8 __attribute__((ext_vector_type(8)));
typedef float floatx4 __attribute__((ext_vector_type(4)));

#define GLOBAL_AS __attribute__((address_space(1)))
#define LDS_AS __attribute__((address_space(3)))

__device__ __forceinline__ unsigned short f2bf_rne(float x) {
  unsigned u = __float_as_uint(x);
  u += 0x7FFFu + ((u >> 16) & 1u);
  return (unsigned short)(u >> 16);
}
__device__ __forceinline__ float bf2f(unsigned short b) {
  return __uint_as_float(((unsigned)b) << 16);
}

// ---------------- kernel 1: fp32 -> bf16 convert + row norms + init ----------------
__global__ __launch_bounds__(256) void prep_kernel(
    const float* __restrict__ X, unsigned short* __restrict__ Xbf,
    float* __restrict__ sq, unsigned long long* __restrict__ posP,
    unsigned long long* __restrict__ negP, float* __restrict__ sums,
    unsigned* __restrict__ cnt) {
  const int row = blockIdx.x;
  const int t = threadIdx.x;
  const float4* xr = (const float4*)(X + (size_t)row * DIM);
  ushort4* br = (ushort4*)(Xbf + (size_t)row * DIM);
  float s = 0.f;
#pragma unroll
  for (int it = 0; it < 2; ++it) {
    int i = t + it * 256;
    float4 v = xr[i];
    ushort4 o;
    o.x = f2bf_rne(v.x); o.y = f2bf_rne(v.y);
    o.z = f2bf_rne(v.z); o.w = f2bf_rne(v.w);
    // norm of the ROUNDED values so d2 is consistent with the MFMA dot
    float b0 = bf2f(o.x), b1 = bf2f(o.y), b2 = bf2f(o.z), b3 = bf2f(o.w);
    s += b0 * b0 + b1 * b1 + b2 * b2 + b3 * b3;
    br[i] = o;
  }
#pragma unroll
  for (int m = 32; m > 0; m >>= 1) s += __shfl_down(s, m, 64);
  __shared__ float ls[4];
  const int w = t >> 6, lane = t & 63;
  if (lane == 0) ls[w] = s;
  __syncthreads();
  if (t == 0) {
    sq[row] = ls[0] + ls[1] + ls[2] + ls[3];
    posP[row] = 0ULL;
    negP[row] = ~0ULL;
    if (row == 0) { sums[0] = 0.f; sums[1] = 0.f; cnt[0] = 0u; }
  }
}

// ---------------- kernel 2: fused Gram GEMM + mining, counted-vmcnt pipeline -------
// R3 (T3+T4 port): 128x128 tiles, BK=32, 4-deep LDS ring (4 x 16 KB = 64 KB),
// 256 threads = 2x2 waves of 64x64 (R1-verified epilogue geometry). Per K-tile:
// one phase {8 ds_read_b128, stage tile t+3 (4 global_load_lds), raw s_barrier,
// 16 MFMA in setprio(1)}. ONE counted s_waitcnt vmcnt(8) per K-tile (never 0
// until the final tile) -- stages stay 3 tiles (~6 phases) in flight, so the
// vmcnt(0)+barrier drain that pinned R0/R2 at MfmaUtil 18% is gone.
// Ledger (4 loads/thread/tile, FIFO): at tile t outstanding <= {t+1,t+2} = 8
// loads, so vmcnt(8) => tile t landed. Tail: t=62 -> vmcnt(4), t=63 -> vmcnt(0).
// WAR: stage targets buf[(t+3)&3] = buf[(t-1)&3]; all reads of it completed
// before this tile's post-vmcnt barrier (data-dep lgkmcnt before MFMA + barrier).
#define BM 128
#define BCN 128
#define BK 32            // K elems per ring slot (64 B per row)
#define NT (DIM / BK)    // 64 K-tiles
#define NBLK 528

__device__ __forceinline__ void async16(const void* g, void* l) {
  __builtin_amdgcn_global_load_lds((GLOBAL_AS unsigned int*)g, (LDS_AS unsigned int*)l,
                                   16, 0, 0);
}

// tile id -> (ry, cx) over upper triangle of 32x32 chunk grid, cx >= ry.
// cum(y) = y*(65-y)/2; XCD swizzle 8x66 (528 = 8*66, bijective)
__device__ __forceinline__ void tile_decode(int tt, int& ry, int& cx) {
  const int t = (tt & 7) * 66 + (tt >> 3);
  int y = (int)((65.0f - sqrtf((float)(4225 - 8 * t))) * 0.5f);
  while ((y + 1) * (64 - y) / 2 <= t) ++y;
  while (y * (65 - y) / 2 > t) --y;
  ry = y;
  cx = y + (t - y * (65 - y) / 2);
}

// bank swizzle for 64 B rows (4 x 16 B slots): slot = chunk ^ kxor(row&15).
// kxor(m) = (m + (m>>2)) & 3 gives each fold-group {m, m+4, m+8, m+12} all 4
// distinct slots -> uniform 2-way bank aliasing on ds_read_b128 (free).
__device__ __forceinline__ int kxor(int m) { return (m + (m >> 2)) & 3; }

// stage one K-tile (A rows w*32..+31, B rows w*32..+31) into ring slot tile&3.
// srcA0/srcB0 are per-lane: Xbf + (r0 + w*32 + rr)*DIM + cg*8, rr=lane>>2,
// cg=(lane&3)^kxor(rr). LDS dest is wave-uniform; DMA writes lane*16 B linear.
__device__ __forceinline__ void stage_tile(
    int tile, const unsigned short* srcA0, const unsigned short* srcB0,
    unsigned short (*Ab)[BM * BK], unsigned short (*Bb)[BCN * BK], int w) {
  const size_t ko = (size_t)tile * BK;
  unsigned short* la = Ab[tile & 3] + (w * 32) * BK;
  unsigned short* lb = Bb[tile & 3] + (w * 32) * BK;
  async16(srcA0 + ko, la);
  async16(srcA0 + (size_t)16 * DIM + ko, la + 16 * BK);
  async16(srcB0 + ko, lb);
  async16(srcB0 + (size_t)16 * DIM + ko, lb + 16 * BK);
}

template <int VM, bool STAGE>
__device__ __forceinline__ void tile_body(
    int t, const unsigned short* srcA0, const unsigned short* srcB0,
    unsigned short (*Ab)[BM * BK], unsigned short (*Bb)[BCN * BK],
    int w, int wr, int wc, int ml, int kq, floatx4 (&acc)[4][4]) {
  if constexpr (VM == 8) asm volatile("s_waitcnt vmcnt(8)" ::: "memory");
  else if constexpr (VM == 4) asm volatile("s_waitcnt vmcnt(4)" ::: "memory");
  else asm volatile("s_waitcnt vmcnt(0)" ::: "memory");
  __builtin_amdgcn_s_barrier();          // tile t fully in LDS for all waves
  __builtin_amdgcn_sched_barrier(0);     // pin: nothing moves above this point
  const unsigned short* At = Ab[t & 3];
  const unsigned short* Bt = Bb[t & 3];
  bf16x8 af[4], bfr[4];
#pragma unroll
  for (int i = 0; i < 4; ++i)
    af[i] = *(const bf16x8*)(At + (wr * 64 + i * 16 + ml) * BK + kq);
#pragma unroll
  for (int j = 0; j < 4; ++j)
    bfr[j] = *(const bf16x8*)(Bt + (wc * 64 + j * 16 + ml) * BK + kq);
  if constexpr (STAGE) stage_tile(t + 3, srcA0, srcB0, Ab, Bb, w);
  __builtin_amdgcn_s_barrier();          // schedule shaping: cluster MFMA
  __builtin_amdgcn_s_setprio(1);
#pragma unroll
  for (int i = 0; i < 4; ++i)
#pragma unroll
    for (int j = 0; j < 4; ++j)
      acc[i][j] = __builtin_amdgcn_mfma_f32_16x16x32_bf16(af[i], bfr[j], acc[i][j], 0, 0, 0);
  __builtin_amdgcn_s_setprio(0);
}

__global__ __launch_bounds__(256, 2) void gemm_mine_kernel(
    const unsigned short* __restrict__ Xbf, const float* __restrict__ sq,
    const int* __restrict__ targets,
    unsigned long long* __restrict__ posP, unsigned long long* __restrict__ negP) {
  int ry, cx;
  tile_decode(blockIdx.x, ry, cx);
  const int r0 = ry * BM;
  const int c0 = cx * BCN;

  __shared__ __align__(16) unsigned short Ab[4][BM * BK];   // 4 x 8 KB
  __shared__ __align__(16) unsigned short Bb[4][BCN * BK];  // 4 x 8 KB
  const int tid = threadIdx.x;
  const int lane = tid & 63;
  const int w = tid >> 6;          // wave 0..3
  const int wr = w >> 1;           // wave row: rows wr*64..+63
  const int wc = w & 1;            // wave col: cols wc*64..+63
  const int quad = lane >> 4;
  const int ml = lane & 15;
  const int kq = (quad ^ kxor(ml)) * 8;   // element offset of my k-chunk's slot

  floatx4 acc[4][4];
#pragma unroll
  for (int i = 0; i < 4; ++i)
#pragma unroll
    for (int j = 0; j < 4; ++j)
#pragma unroll
      for (int k = 0; k < 4; ++k) acc[i][j][k] = 0.f;

  // per-lane staging source: row rr = lane>>2 of my wave's 16-row group,
  // global chunk cg = (lane&3) ^ kxor(rr)  (inverse of the read swizzle).
  const int rr = lane >> 2;
  const int cg = (lane & 3) ^ kxor(rr);
  const unsigned short* srcA0 = Xbf + (size_t)(r0 + w * 32 + rr) * DIM + cg * 8;
  const unsigned short* srcB0 = Xbf + (size_t)(c0 + w * 32 + rr) * DIM + cg * 8;

  // prologue: prime the ring with tiles 0,1,2 (12 loads/thread in flight)
  stage_tile(0, srcA0, srcB0, Ab, Bb, w);
  stage_tile(1, srcA0, srcB0, Ab, Bb, w);
  stage_tile(2, srcA0, srcB0, Ab, Bb, w);

#pragma unroll 4
  for (int t = 0; t < NT - 3; ++t)
    tile_body<8, true>(t, srcA0, srcB0, Ab, Bb, w, wr, wc, ml, kq, acc);
  tile_body<8, false>(NT - 3, srcA0, srcB0, Ab, Bb, w, wr, wc, ml, kq, acc);
  tile_body<4, false>(NT - 2, srcA0, srcB0, Ab, Bb, w, wr, wc, ml, kq, acc);
  tile_body<0, false>(NT - 1, srcA0, srcB0, Ab, Bb, w, wr, wc, ml, kq, acc);

  // epilogue A: row-direction mining. C/D layout: col = lane&15, row = quad*4+reg.
  // (geometry identical to R1's verified 128^2 epilogue)
  const int cl = ml;
#pragma unroll
  for (int i = 0; i < 4; ++i) {
#pragma unroll
    for (int rg = 0; rg < 4; ++rg) {
      const int gr = r0 + wr * 64 + i * 16 + quad * 4 + rg;
      const int tgt_r = targets[gr];
      const float sqr = sq[gr];
      unsigned long long pm = 0ULL;
      unsigned long long nm = ~0ULL;
#pragma unroll
      for (int j = 0; j < 4; ++j) {
        const int gc = c0 + wc * 64 + j * 16 + cl;
        const float d2 = sqr + sq[gc] - 2.0f * acc[i][j][rg];
        const float dist = sqrtf(fmaxf(d2, 1e-12f));
        const unsigned long long ph = ((unsigned long long)__float_as_uint(dist)) << 32;
        if (targets[gc] == tgt_r) {
          // argmax first-index tiebreak: larger (4095-gc) == smaller gc wins on ties
          unsigned long long cand = ph | (unsigned)(4095 - gc);
          pm = pm > cand ? pm : cand;
        } else {
          unsigned long long cand = ph | (unsigned)gc;
          nm = nm < cand ? nm : cand;
        }
      }
#pragma unroll
      for (int m = 1; m < 16; m <<= 1) {
        unsigned long long pmo = __shfl_xor(pm, m, 64);
        unsigned long long nmo = __shfl_xor(nm, m, 64);
        pm = pm > pmo ? pm : pmo;
        nm = nm < nmo ? nm : nmo;
      }
      if (cl == 0) {
        atomicMax(&posP[gr], pm);
        atomicMin(&negP[gr], nm);
      }
    }
  }

  // epilogue B: transposed mining (off-diagonal tiles only; diagonal tiles hold
  // the full 128x128 square so row passes already cover both orders).
  if (cx > ry) {
#pragma unroll
    for (int j = 0; j < 4; ++j) {
      const int gc = c0 + wc * 64 + j * 16 + cl;
      const int tgt_c = targets[gc];
      const float sqc = sq[gc];
      unsigned long long pm = 0ULL;
      unsigned long long nm = ~0ULL;
#pragma unroll
      for (int i = 0; i < 4; ++i) {
#pragma unroll
        for (int rg = 0; rg < 4; ++rg) {
          const int gr = r0 + wr * 64 + i * 16 + quad * 4 + rg;
          const float d2 = sq[gr] + sqc - 2.0f * acc[i][j][rg];
          const float dist = sqrtf(fmaxf(d2, 1e-12f));
          const unsigned long long ph = ((unsigned long long)__float_as_uint(dist)) << 32;
          if (targets[gr] == tgt_c) {
            unsigned long long cand = ph | (unsigned)(4095 - gr);
            pm = pm > cand ? pm : cand;
          } else {
            unsigned long long cand = ph | (unsigned)gr;
            nm = nm < cand ? nm : cand;
          }
        }
      }
#pragma unroll
      for (int m = 16; m < 64; m <<= 1) {
        unsigned long long pmo = __shfl_xor(pm, m, 64);
        unsigned long long nmo = __shfl_xor(nm, m, 64);
        pm = pm > pmo ? pm : pmo;
        nm = nm < nmo ? nm : nmo;
      }
      if (quad == 0) {
        atomicMax(&posP[gc], pm);
        atomicMin(&negP[gc], nm);
      }
    }
  }
}

// ---------------- kernel 3: local DTW distances + both loss sums + finalize --------
__global__ __launch_bounds__(256) void local_dtw_kernel(
    const float* __restrict__ LF, const unsigned long long* __restrict__ posP,
    const unsigned long long* __restrict__ negP, float* __restrict__ sums,
    unsigned* __restrict__ cnt, float* __restrict__ out) {
  __shared__ float bufA[4][1024];
  __shared__ float bufP[4][1024];
  __shared__ float bufN[4][1024];
  __shared__ float dmP[4][64];
  __shared__ float dmN[4][64];
  __shared__ float gterms[4], lterms[4];
  const int w = threadIdx.x >> 6, lane = threadIdx.x & 63;
  const int a = blockIdx.x * 4 + w;
  const unsigned long long pp = posP[a];
  const unsigned long long nn = negP[a];
  const int p_ind = 4095 - (int)(pp & 0xFFFFFFFFULL);
  const int n_ind = (int)(nn & 0xFFFFFFFFULL);
  const float dist_ap = __uint_as_float((unsigned)(pp >> 32));
  const float dist_an = __uint_as_float((unsigned)(nn >> 32));

  const float4* ga = (const float4*)(LF + (size_t)a * 1024);
  const float4* gp = (const float4*)(LF + (size_t)p_ind * 1024);
  const float4* gn = (const float4*)(LF + (size_t)n_ind * 1024);
  float4* la = (float4*)bufA[w];
  float4* lp = (float4*)bufP[w];
  float4* ln_ = (float4*)bufN[w];
#pragma unroll
  for (int i = 0; i < 4; ++i) {
    la[lane + i * 64] = ga[lane + i * 64];
    lp[lane + i * 64] = gp[lane + i * 64];
    ln_[lane + i * 64] = gn[lane + i * 64];
  }
  __syncthreads();
  const int t1 = lane >> 3, t2 = lane & 7;
  float sp = 0.f, sn = 0.f;
#pragma unroll 8
  for (int d = 0; d < 128; ++d) {
    float xa = bufA[w][d * 8 + t1];
    float xp = bufP[w][d * 8 + t2];
    float xn = bufN[w][d * 8 + t2];
    float e1 = xa - xp; sp += e1 * e1;
    float e2 = xa - xn; sn += e2 * e2;
  }
  dmP[w][lane] = tanhf(0.5f * sqrtf(fmaxf(sp, 1e-12f)));  // == (e^d-1)/(e^d+1)
  dmN[w][lane] = tanhf(0.5f * sqrtf(fmaxf(sn, 1e-12f)));
  __syncthreads();
  // two serial 8x8 DPs per wave run concurrently on lanes 0 and 1
  if (lane < 2) {
    const float* dm = (lane == 0) ? dmP[w] : dmN[w];
    float row[8];
    row[0] = dm[0];
#pragma unroll
    for (int j = 1; j < 8; ++j) row[j] = row[j - 1] + dm[j];
#pragma unroll
    for (int i = 1; i < 8; ++i) {
      row[0] = row[0] + dm[i * 8];
#pragma unroll
      for (int j = 1; j < 8; ++j) row[j] = fminf(row[j], row[j - 1]) + dm[i * 8 + j];
    }
    if (lane == 0) dmP[w][0] = row[7];   // reuse LDS slot to pass ap
    else dmN[w][0] = row[7];             // an
  }
  __syncthreads();
  if (lane == 0) {
    gterms[w] = fmaxf(dist_ap - dist_an + MARGINF, 0.f);
    lterms[w] = fmaxf(dmP[w][0] - dmN[w][0] + MARGINF, 0.f);
  }
  __syncthreads();
  if (threadIdx.x == 0) {
    atomicAdd(&sums[0], gterms[0] + gterms[1] + gterms[2] + gterms[3]);
    atomicAdd(&sums[1], lterms[0] + lterms[1] + lterms[2] + lterms[3]);
    __threadfence();
    const unsigned v = atomicAdd(cnt, 1u);
    if (v == gridDim.x - 1) {
      // last block: all other blocks' sums-adds happened-before their cnt add.
      const float s0 = atomicAdd(&sums[0], 0.f);
      const float s1 = atomicAdd(&sums[1], 0.f);
      out[0] = s0 * (1.0f / 4096.0f);
      out[1] = s1 * (1.0f / 4096.0f);
    }
  }
}

extern "C" void kernel_launch(void* const* d_in, const int* in_sizes, int n_in,
                              void* d_out, int out_size, void* d_ws, size_t ws_size,
                              hipStream_t stream) {
  const float* X = (const float*)d_in[0];
  const int* targets = (const int*)d_in[1];
  const float* LF = (const float*)d_in[2];
  float* out = (float*)d_out;

  char* ws = (char*)d_ws;
  size_t off = 0;
  unsigned short* Xbf = (unsigned short*)(ws + off); off += (size_t)NS * DIM * 2;  // 16 MB
  float* sq = (float*)(ws + off); off += (size_t)NS * 4;
  off = (off + 255) & ~(size_t)255;
  unsigned long long* posP = (unsigned long long*)(ws + off); off += (size_t)NS * 8;
  unsigned long long* negP = (unsigned long long*)(ws + off); off += (size_t)NS * 8;
  float* sums = (float*)(ws + off); off += 256;
  unsigned* cnt = (unsigned*)(ws + off); off += 256;

  prep_kernel<<<NS, 256, 0, stream>>>(X, Xbf, sq, posP, negP, sums, cnt);
  gemm_mine_kernel<<<NBLK, 256, 0, stream>>>(Xbf, sq, targets, posP, negP);
  local_dtw_kernel<<<NS / 4, 256, 0, stream>>>(LF, posP, negP, sums, cnt, out);
}

// Round 4
// 168.258 us; speedup vs baseline: 1.3872x; 1.3872x over previous
//
#include <hip/hip_runtime.h>
#include <stdint.h>

#define NS 4096
#define DIM 2048
#define MARGINF 0.3f

typedef __bf16 bf16x8 __attribute__((ext_vector_type(8)));
typedef float floatx4 __attribute__((ext_vector_type(4)));

#define GLOBAL_AS __attribute__((address_space(1)))
#define LDS_AS __attribute__((address_space(3)))

__device__ __forceinline__ unsigned short f2bf_rne(float x) {
  unsigned u = __float_as_uint(x);
  u += 0x7FFFu + ((u >> 16) & 1u);
  return (unsigned short)(u >> 16);
}
__device__ __forceinline__ float bf2f(unsigned short b) {
  return __uint_as_float(((unsigned)b) << 16);
}

// ---------------- kernel 1: fp32 -> bf16 convert + row norms + init ----------------
__global__ __launch_bounds__(256) void prep_kernel(
    const float* __restrict__ X, unsigned short* __restrict__ Xbf,
    float* __restrict__ sq, unsigned long long* __restrict__ posP,
    unsigned long long* __restrict__ negP) {
  const int row = blockIdx.x;
  const int t = threadIdx.x;
  const float4* xr = (const float4*)(X + (size_t)row * DIM);
  ushort4* br = (ushort4*)(Xbf + (size_t)row * DIM);
  float s = 0.f;
#pragma unroll
  for (int it = 0; it < 2; ++it) {
    int i = t + it * 256;
    float4 v = xr[i];
    ushort4 o;
    o.x = f2bf_rne(v.x); o.y = f2bf_rne(v.y);
    o.z = f2bf_rne(v.z); o.w = f2bf_rne(v.w);
    // norm of the ROUNDED values so d2 is consistent with the MFMA dot
    float b0 = bf2f(o.x), b1 = bf2f(o.y), b2 = bf2f(o.z), b3 = bf2f(o.w);
    s += b0 * b0 + b1 * b1 + b2 * b2 + b3 * b3;
    br[i] = o;
  }
#pragma unroll
  for (int m = 32; m > 0; m >>= 1) s += __shfl_down(s, m, 64);
  __shared__ float ls[4];
  const int w = t >> 6, lane = t & 63;
  if (lane == 0) ls[w] = s;
  __syncthreads();
  if (t == 0) {
    sq[row] = ls[0] + ls[1] + ls[2] + ls[3];
    posP[row] = 0ULL;
    negP[row] = ~0ULL;
  }
}

// ---------------- kernel 2: fused Gram GEMM + mining (R2-proven, 77 us) ------------
// 128x64 tiles, 1056 blocks (4.1 queued/CU — cross-block overlap is the proven
// latency-hiding mechanism for the 2-barrier loop), 2 waves per block, each wave
// a 64x64 sub-tile: 16 ds_read_b128 : 32 MFMA per K-step. Deep in-block
// pipelining on this geometry is a proven dead end (R3 here; m232 128^2+8ph
// quadrant) — do not re-attempt without the full 8-wave/256^2 derived-waits port.
#define BM 128
#define BCN 64           // tile cols
#define BKE 64           // K elems staged per iter (128 B per row)
#define NBLK 1056

__device__ __forceinline__ void async16(const void* g, void* l) {
  __builtin_amdgcn_global_load_lds((GLOBAL_AS unsigned int*)g, (LDS_AS unsigned int*)l,
                                   16, 0, 0);
}

// tile id -> (ry, cx); cum(y) = y*(65-y) tiles precede row-chunk y; XCD swizzle 8x132
__device__ __forceinline__ void tile_decode(int tt, int& ry, int& cx) {
  const int t = (tt & 7) * 132 + (tt >> 3);
  int y = (int)((65.0f - sqrtf((float)(4225 - 4 * t))) * 0.5f);
  while ((y + 1) * (64 - y) <= t) ++y;   // cum(y+1) = (y+1)*(64-y)
  while (y * (65 - y) > t) --y;
  ry = y;
  cx = 2 * y + (t - y * (65 - y));
}

__global__ __launch_bounds__(128, 3) void gemm_mine_kernel(
    const unsigned short* __restrict__ Xbf, const float* __restrict__ sq,
    const int* __restrict__ targets,
    unsigned long long* __restrict__ posP, unsigned long long* __restrict__ negP) {
  int ry, cx;
  tile_decode(blockIdx.x, ry, cx);
  const int r0 = ry * BM;
  const int c0 = cx * BCN;

  __shared__ __align__(16) unsigned short Ab[BM * BKE];   // 16 KB
  __shared__ __align__(16) unsigned short Bb[BCN * BKE];  //  8 KB
  const int tid = threadIdx.x;
  const int lane = tid & 63;
  const int w = tid >> 6;          // wave 0..1: rows w*64..w*64+63, all 64 cols
  const int quad = lane >> 4;
  const int ml = lane & 15;

  floatx4 acc[4][4];
#pragma unroll
  for (int i = 0; i < 4; ++i)
#pragma unroll
    for (int j = 0; j < 4; ++j)
#pragma unroll
      for (int k = 0; k < 4; ++k) acc[i][j][k] = 0.f;

  // staging (verified conflict-free): row = 8 chunks of 16 B; chunk c of row R at
  // slot c ^ (R&7); DMA lane -> (row lane>>3, slot lane&7) so lane fetches global
  // chunk (lane&7)^((lane>>3)&7). Each async16 = 8 rows x 128 B.
  // wave w stages A rows w*64..+63 (8 issues) and B rows w*32..+31 (4 issues).
  const int r_rel = lane >> 3;
  const int c_g = (lane & 7) ^ r_rel;
  const unsigned short* gA = Xbf + (size_t)(r0 + w * 64 + r_rel) * DIM + c_g * 8;
  const unsigned short* gB = Xbf + (size_t)(c0 + w * 32 + r_rel) * DIM + c_g * 8;
  unsigned short* lA = Ab + w * 64 * BKE;
  unsigned short* lB = Bb + w * 32 * BKE;
  const int sx = ml & 7;

  for (int k0 = 0; k0 < DIM; k0 += BKE) {
    __syncthreads();
#pragma unroll
    for (int q = 0; q < 8; ++q)
      async16(gA + (size_t)(q * 8) * DIM + k0, lA + q * 8 * BKE);
#pragma unroll
    for (int q = 0; q < 4; ++q)
      async16(gB + (size_t)(q * 8) * DIM + k0, lB + q * 8 * BKE);
    __syncthreads();   // vmcnt(0) drain
#pragma unroll
    for (int h = 0; h < 2; ++h) {
      const int slot = ((h << 2) + quad) ^ sx;
      bf16x8 af[4], bfr[4];
#pragma unroll
      for (int i = 0; i < 4; ++i)
        af[i] = *(const bf16x8*)(Ab + ((w * 64 + i * 16 + ml) * BKE) + slot * 8);
#pragma unroll
      for (int j = 0; j < 4; ++j)
        bfr[j] = *(const bf16x8*)(Bb + ((j * 16 + ml) * BKE) + slot * 8);
#pragma unroll
      for (int i = 0; i < 4; ++i)
#pragma unroll
        for (int j = 0; j < 4; ++j)
          acc[i][j] = __builtin_amdgcn_mfma_f32_16x16x32_bf16(af[i], bfr[j], acc[i][j], 0, 0, 0);
    }
  }

  // epilogue A: row-direction mining. C/D layout: col = lane&15, row = quad*4+reg.
  const int cl = ml;
#pragma unroll
  for (int i = 0; i < 4; ++i) {
#pragma unroll
    for (int rg = 0; rg < 4; ++rg) {
      const int gr = r0 + w * 64 + i * 16 + quad * 4 + rg;
      const int tgt_r = targets[gr];
      const float sqr = sq[gr];
      unsigned long long pm = 0ULL;
      unsigned long long nm = ~0ULL;
#pragma unroll
      for (int j = 0; j < 4; ++j) {
        const int gc = c0 + j * 16 + cl;
        const float d2 = sqr + sq[gc] - 2.0f * acc[i][j][rg];
        const float dist = sqrtf(fmaxf(d2, 1e-12f));
        const unsigned long long ph = ((unsigned long long)__float_as_uint(dist)) << 32;
        if (targets[gc] == tgt_r) {
          // argmax first-index tiebreak: larger (4095-gc) == smaller gc wins on ties
          unsigned long long cand = ph | (unsigned)(4095 - gc);
          pm = pm > cand ? pm : cand;
        } else {
          unsigned long long cand = ph | (unsigned)gc;
          nm = nm < cand ? nm : cand;
        }
      }
#pragma unroll
      for (int m = 1; m < 16; m <<= 1) {
        unsigned long long pmo = __shfl_xor(pm, m, 64);
        unsigned long long nmo = __shfl_xor(nm, m, 64);
        pm = pm > pmo ? pm : pmo;
        nm = nm < nmo ? nm : nmo;
      }
      if (cl == 0) {
        atomicMax(&posP[gr], pm);
        atomicMin(&negP[gr], nm);
      }
    }
  }

  // epilogue B: transposed mining (only when col-range is outside the row-range;
  // for cx in {2ry, 2ry+1} both orderings already appear in row passes).
  if (cx >= 2 * ry + 2) {
#pragma unroll
    for (int j = 0; j < 4; ++j) {
      const int gc = c0 + j * 16 + cl;
      const int tgt_c = targets[gc];
      const float sqc = sq[gc];
      unsigned long long pm = 0ULL;
      unsigned long long nm = ~0ULL;
#pragma unroll
      for (int i = 0; i < 4; ++i) {
#pragma unroll
        for (int rg = 0; rg < 4; ++rg) {
          const int gr = r0 + w * 64 + i * 16 + quad * 4 + rg;
          const float d2 = sq[gr] + sqc - 2.0f * acc[i][j][rg];
          const float dist = sqrtf(fmaxf(d2, 1e-12f));
          const unsigned long long ph = ((unsigned long long)__float_as_uint(dist)) << 32;
          if (targets[gr] == tgt_c) {
            unsigned long long cand = ph | (unsigned)(4095 - gr);
            pm = pm > cand ? pm : cand;
          } else {
            unsigned long long cand = ph | (unsigned)gr;
            nm = nm < cand ? nm : cand;
          }
        }
      }
#pragma unroll
      for (int m = 16; m < 64; m <<= 1) {
        unsigned long long pmo = __shfl_xor(pm, m, 64);
        unsigned long long nmo = __shfl_xor(nm, m, 64);
        pm = pm > pmo ? pm : pmo;
        nm = nm < nmo ? nm : nmo;
      }
      if (quad == 0) {
        atomicMax(&posP[gc], pm);
        atomicMin(&negP[gc], nm);
      }
    }
  }
}

// ---------------- kernel 3: local DTW distances -> per-block partial sums ----------
// R4: NO contended atomics / fences. Each block stores one float2 partial
// (sum of 4 anchors' global-term and local-term); finalize reduces 1024 partials.
__global__ __launch_bounds__(256) void local_dtw_kernel(
    const float* __restrict__ LF, const unsigned long long* __restrict__ posP,
    const unsigned long long* __restrict__ negP, float2* __restrict__ parts) {
  __shared__ float bufA[4][1024];
  __shared__ float bufP[4][1024];
  __shared__ float bufN[4][1024];
  __shared__ float dmP[4][64];
  __shared__ float dmN[4][64];
  __shared__ float gterms[4], lterms[4];
  const int w = threadIdx.x >> 6, lane = threadIdx.x & 63;
  const int a = blockIdx.x * 4 + w;
  const unsigned long long pp = posP[a];
  const unsigned long long nn = negP[a];
  const int p_ind = 4095 - (int)(pp & 0xFFFFFFFFULL);
  const int n_ind = (int)(nn & 0xFFFFFFFFULL);
  const float dist_ap = __uint_as_float((unsigned)(pp >> 32));
  const float dist_an = __uint_as_float((unsigned)(nn >> 32));

  const float4* ga = (const float4*)(LF + (size_t)a * 1024);
  const float4* gp = (const float4*)(LF + (size_t)p_ind * 1024);
  const float4* gn = (const float4*)(LF + (size_t)n_ind * 1024);
  float4* la = (float4*)bufA[w];
  float4* lp = (float4*)bufP[w];
  float4* ln_ = (float4*)bufN[w];
#pragma unroll
  for (int i = 0; i < 4; ++i) {
    la[lane + i * 64] = ga[lane + i * 64];
    lp[lane + i * 64] = gp[lane + i * 64];
    ln_[lane + i * 64] = gn[lane + i * 64];
  }
  __syncthreads();
  const int t1 = lane >> 3, t2 = lane & 7;
  float sp = 0.f, sn = 0.f;
#pragma unroll 8
  for (int d = 0; d < 128; ++d) {
    float xa = bufA[w][d * 8 + t1];
    float xp = bufP[w][d * 8 + t2];
    float xn = bufN[w][d * 8 + t2];
    float e1 = xa - xp; sp += e1 * e1;
    float e2 = xa - xn; sn += e2 * e2;
  }
  dmP[w][lane] = tanhf(0.5f * sqrtf(fmaxf(sp, 1e-12f)));  // == (e^d-1)/(e^d+1)
  dmN[w][lane] = tanhf(0.5f * sqrtf(fmaxf(sn, 1e-12f)));
  __syncthreads();
  // two serial 8x8 DPs per wave run concurrently on lanes 0 and 1
  if (lane < 2) {
    const float* dm = (lane == 0) ? dmP[w] : dmN[w];
    float row[8];
    row[0] = dm[0];
#pragma unroll
    for (int j = 1; j < 8; ++j) row[j] = row[j - 1] + dm[j];
#pragma unroll
    for (int i = 1; i < 8; ++i) {
      row[0] = row[0] + dm[i * 8];
#pragma unroll
      for (int j = 1; j < 8; ++j) row[j] = fminf(row[j], row[j - 1]) + dm[i * 8 + j];
    }
    if (lane == 0) dmP[w][0] = row[7];   // reuse LDS slot to pass ap
    else dmN[w][0] = row[7];             // an
  }
  __syncthreads();
  if (lane == 0) {
    gterms[w] = fmaxf(dist_ap - dist_an + MARGINF, 0.f);
    lterms[w] = fmaxf(dmP[w][0] - dmN[w][0] + MARGINF, 0.f);
  }
  __syncthreads();
  if (threadIdx.x == 0) {
    parts[blockIdx.x] = make_float2(gterms[0] + gterms[1] + gterms[2] + gterms[3],
                                    lterms[0] + lterms[1] + lterms[2] + lterms[3]);
  }
}

// ---------------- kernel 4: finalize — reduce 1024 partials, write out -------------
__global__ __launch_bounds__(256) void finalize_kernel(
    const float2* __restrict__ parts, float* __restrict__ out) {
  const int t = threadIdx.x;
  float g = 0.f, l = 0.f;
#pragma unroll
  for (int i = 0; i < 4; ++i) {
    float2 v = parts[t + i * 256];
    g += v.x; l += v.y;
  }
#pragma unroll
  for (int m = 32; m > 0; m >>= 1) {
    g += __shfl_down(g, m, 64);
    l += __shfl_down(l, m, 64);
  }
  __shared__ float sg[4], sl[4];
  if ((t & 63) == 0) { sg[t >> 6] = g; sl[t >> 6] = l; }
  __syncthreads();
  if (t == 0) {
    out[0] = (sg[0] + sg[1] + sg[2] + sg[3]) * (1.0f / 4096.0f);
    out[1] = (sl[0] + sl[1] + sl[2] + sl[3]) * (1.0f / 4096.0f);
  }
}

extern "C" void kernel_launch(void* const* d_in, const int* in_sizes, int n_in,
                              void* d_out, int out_size, void* d_ws, size_t ws_size,
                              hipStream_t stream) {
  const float* X = (const float*)d_in[0];
  const int* targets = (const int*)d_in[1];
  const float* LF = (const float*)d_in[2];
  float* out = (float*)d_out;

  char* ws = (char*)d_ws;
  size_t off = 0;
  unsigned short* Xbf = (unsigned short*)(ws + off); off += (size_t)NS * DIM * 2;  // 16 MB
  float* sq = (float*)(ws + off); off += (size_t)NS * 4;
  off = (off + 255) & ~(size_t)255;
  unsigned long long* posP = (unsigned long long*)(ws + off); off += (size_t)NS * 8;
  unsigned long long* negP = (unsigned long long*)(ws + off); off += (size_t)NS * 8;
  float2* parts = (float2*)(ws + off); off += (size_t)(NS / 4) * 8;

  prep_kernel<<<NS, 256, 0, stream>>>(X, Xbf, sq, posP, negP);
  gemm_mine_kernel<<<NBLK, 128, 0, stream>>>(Xbf, sq, targets, posP, negP);
  local_dtw_kernel<<<NS / 4, 256, 0, stream>>>(LF, posP, negP, parts);
  finalize_kernel<<<1, 256, 0, stream>>>(parts, out);
}

// Round 5
// 166.923 us; speedup vs baseline: 1.3983x; 1.0080x over previous
//
#include <hip/hip_runtime.h>
#include <stdint.h>

#define NS 4096
#define DIM 2048
#define MARGINF 0.3f

typedef __bf16 bf16x8 __attribute__((ext_vector_type(8)));
typedef float floatx4 __attribute__((ext_vector_type(4)));

#define GLOBAL_AS __attribute__((address_space(1)))
#define LDS_AS __attribute__((address_space(3)))

__device__ __forceinline__ unsigned short f2bf_rne(float x) {
  unsigned u = __float_as_uint(x);
  u += 0x7FFFu + ((u >> 16) & 1u);
  return (unsigned short)(u >> 16);
}
__device__ __forceinline__ float bf2f(unsigned short b) {
  return __uint_as_float(((unsigned)b) << 16);
}

// ---------------- kernel 1: fp32 -> bf16 convert + row norms + init ----------------
// R5: one row per WAVE (1024 blocks x 4 waves): 8 float4 chunks/lane, pure-shfl
// reduction, no LDS / no barriers (old version: 4096 tiny blocks + 2 barriers each).
__global__ __launch_bounds__(256) void prep_kernel(
    const float* __restrict__ X, unsigned short* __restrict__ Xbf,
    float* __restrict__ sq, unsigned long long* __restrict__ posP,
    unsigned long long* __restrict__ negP) {
  const int w = threadIdx.x >> 6, lane = threadIdx.x & 63;
  const int row = blockIdx.x * 4 + w;
  const float4* xr = (const float4*)(X + (size_t)row * DIM);
  ushort4* br = (ushort4*)(Xbf + (size_t)row * DIM);
  float s = 0.f;
#pragma unroll
  for (int i = 0; i < 8; ++i) {
    float4 v = xr[lane + i * 64];
    ushort4 o;
    o.x = f2bf_rne(v.x); o.y = f2bf_rne(v.y);
    o.z = f2bf_rne(v.z); o.w = f2bf_rne(v.w);
    // norm of the ROUNDED values so d2 is consistent with the MFMA dot
    float b0 = bf2f(o.x), b1 = bf2f(o.y), b2 = bf2f(o.z), b3 = bf2f(o.w);
    s += b0 * b0 + b1 * b1 + b2 * b2 + b3 * b3;
    br[lane + i * 64] = o;
  }
#pragma unroll
  for (int m = 32; m > 0; m >>= 1) s += __shfl_down(s, m, 64);
  if (lane == 0) {
    sq[row] = s;
    posP[row] = 0ULL;
    negP[row] = ~0ULL;
  }
}

// ---------------- kernel 2: fused Gram GEMM + mining (R2-proven, 77 us) ------------
// 128x64 tiles, 1056 blocks (4.1 queued/CU — cross-block overlap is the proven
// latency-hiding mechanism for the 2-barrier loop), 2 waves per block, each wave
// a 64x64 sub-tile: 16 ds_read_b128 : 32 MFMA per K-step. Deep in-block
// pipelining on this geometry is a proven dead end (R3 here; m232 128^2+8ph
// quadrant) — do not re-attempt without the full 8-wave/256^2 derived-waits port.
// NOTE: triangle at 77 us == ~920 TF full-square-equivalent == m97 ceiling.
#define BM 128
#define BCN 64           // tile cols
#define BKE 64           // K elems staged per iter (128 B per row)
#define NBLK 1056

__device__ __forceinline__ void async16(const void* g, void* l) {
  __builtin_amdgcn_global_load_lds((GLOBAL_AS unsigned int*)g, (LDS_AS unsigned int*)l,
                                   16, 0, 0);
}

// tile id -> (ry, cx); cum(y) = y*(65-y) tiles precede row-chunk y; XCD swizzle 8x132
__device__ __forceinline__ void tile_decode(int tt, int& ry, int& cx) {
  const int t = (tt & 7) * 132 + (tt >> 3);
  int y = (int)((65.0f - sqrtf((float)(4225 - 4 * t))) * 0.5f);
  while ((y + 1) * (64 - y) <= t) ++y;   // cum(y+1) = (y+1)*(64-y)
  while (y * (65 - y) > t) --y;
  ry = y;
  cx = 2 * y + (t - y * (65 - y));
}

__global__ __launch_bounds__(128, 3) void gemm_mine_kernel(
    const unsigned short* __restrict__ Xbf, const float* __restrict__ sq,
    const int* __restrict__ targets,
    unsigned long long* __restrict__ posP, unsigned long long* __restrict__ negP) {
  int ry, cx;
  tile_decode(blockIdx.x, ry, cx);
  const int r0 = ry * BM;
  const int c0 = cx * BCN;

  __shared__ __align__(16) unsigned short Ab[BM * BKE];   // 16 KB
  __shared__ __align__(16) unsigned short Bb[BCN * BKE];  //  8 KB
  const int tid = threadIdx.x;
  const int lane = tid & 63;
  const int w = tid >> 6;          // wave 0..1: rows w*64..w*64+63, all 64 cols
  const int quad = lane >> 4;
  const int ml = lane & 15;

  floatx4 acc[4][4];
#pragma unroll
  for (int i = 0; i < 4; ++i)
#pragma unroll
    for (int j = 0; j < 4; ++j)
#pragma unroll
      for (int k = 0; k < 4; ++k) acc[i][j][k] = 0.f;

  // staging (verified conflict-free): row = 8 chunks of 16 B; chunk c of row R at
  // slot c ^ (R&7); DMA lane -> (row lane>>3, slot lane&7) so lane fetches global
  // chunk (lane&7)^((lane>>3)&7). Each async16 = 8 rows x 128 B.
  // wave w stages A rows w*64..+63 (8 issues) and B rows w*32..+31 (4 issues).
  const int r_rel = lane >> 3;
  const int c_g = (lane & 7) ^ r_rel;
  const unsigned short* gA = Xbf + (size_t)(r0 + w * 64 + r_rel) * DIM + c_g * 8;
  const unsigned short* gB = Xbf + (size_t)(c0 + w * 32 + r_rel) * DIM + c_g * 8;
  unsigned short* lA = Ab + w * 64 * BKE;
  unsigned short* lB = Bb + w * 32 * BKE;
  const int sx = ml & 7;

  for (int k0 = 0; k0 < DIM; k0 += BKE) {
    __syncthreads();
#pragma unroll
    for (int q = 0; q < 8; ++q)
      async16(gA + (size_t)(q * 8) * DIM + k0, lA + q * 8 * BKE);
#pragma unroll
    for (int q = 0; q < 4; ++q)
      async16(gB + (size_t)(q * 8) * DIM + k0, lB + q * 8 * BKE);
    __syncthreads();   // vmcnt(0) drain
#pragma unroll
    for (int h = 0; h < 2; ++h) {
      const int slot = ((h << 2) + quad) ^ sx;
      bf16x8 af[4], bfr[4];
#pragma unroll
      for (int i = 0; i < 4; ++i)
        af[i] = *(const bf16x8*)(Ab + ((w * 64 + i * 16 + ml) * BKE) + slot * 8);
#pragma unroll
      for (int j = 0; j < 4; ++j)
        bfr[j] = *(const bf16x8*)(Bb + ((j * 16 + ml) * BKE) + slot * 8);
#pragma unroll
      for (int i = 0; i < 4; ++i)
#pragma unroll
        for (int j = 0; j < 4; ++j)
          acc[i][j] = __builtin_amdgcn_mfma_f32_16x16x32_bf16(af[i], bfr[j], acc[i][j], 0, 0, 0);
    }
  }

  // epilogue A: row-direction mining. C/D layout: col = lane&15, row = quad*4+reg.
  const int cl = ml;
#pragma unroll
  for (int i = 0; i < 4; ++i) {
#pragma unroll
    for (int rg = 0; rg < 4; ++rg) {
      const int gr = r0 + w * 64 + i * 16 + quad * 4 + rg;
      const int tgt_r = targets[gr];
      const float sqr = sq[gr];
      unsigned long long pm = 0ULL;
      unsigned long long nm = ~0ULL;
#pragma unroll
      for (int j = 0; j < 4; ++j) {
        const int gc = c0 + j * 16 + cl;
        const float d2 = sqr + sq[gc] - 2.0f * acc[i][j][rg];
        const float dist = sqrtf(fmaxf(d2, 1e-12f));
        const unsigned long long ph = ((unsigned long long)__float_as_uint(dist)) << 32;
        if (targets[gc] == tgt_r) {
          // argmax first-index tiebreak: larger (4095-gc) == smaller gc wins on ties
          unsigned long long cand = ph | (unsigned)(4095 - gc);
          pm = pm > cand ? pm : cand;
        } else {
          unsigned long long cand = ph | (unsigned)gc;
          nm = nm < cand ? nm : cand;
        }
      }
#pragma unroll
      for (int m = 1; m < 16; m <<= 1) {
        unsigned long long pmo = __shfl_xor(pm, m, 64);
        unsigned long long nmo = __shfl_xor(nm, m, 64);
        pm = pm > pmo ? pm : pmo;
        nm = nm < nmo ? nm : nmo;
      }
      if (cl == 0) {
        atomicMax(&posP[gr], pm);
        atomicMin(&negP[gr], nm);
      }
    }
  }

  // epilogue B: transposed mining (only when col-range is outside the row-range;
  // for cx in {2ry, 2ry+1} both orderings already appear in row passes).
  if (cx >= 2 * ry + 2) {
#pragma unroll
    for (int j = 0; j < 4; ++j) {
      const int gc = c0 + j * 16 + cl;
      const int tgt_c = targets[gc];
      const float sqc = sq[gc];
      unsigned long long pm = 0ULL;
      unsigned long long nm = ~0ULL;
#pragma unroll
      for (int i = 0; i < 4; ++i) {
#pragma unroll
        for (int rg = 0; rg < 4; ++rg) {
          const int gr = r0 + w * 64 + i * 16 + quad * 4 + rg;
          const float d2 = sq[gr] + sqc - 2.0f * acc[i][j][rg];
          const float dist = sqrtf(fmaxf(d2, 1e-12f));
          const unsigned long long ph = ((unsigned long long)__float_as_uint(dist)) << 32;
          if (targets[gr] == tgt_c) {
            unsigned long long cand = ph | (unsigned)(4095 - gr);
            pm = pm > cand ? pm : cand;
          } else {
            unsigned long long cand = ph | (unsigned)gr;
            nm = nm < cand ? nm : cand;
          }
        }
      }
#pragma unroll
      for (int m = 16; m < 64; m <<= 1) {
        unsigned long long pmo = __shfl_xor(pm, m, 64);
        unsigned long long nmo = __shfl_xor(nm, m, 64);
        pm = pm > pmo ? pm : pmo;
        nm = nm < nmo ? nm : nmo;
      }
      if (quad == 0) {
        atomicMax(&posP[gc], pm);
        atomicMin(&negP[gc], nm);
      }
    }
  }
}

// ---------------- kernel 3: local DTW distances -> per-block partial sums ----------
// R5: P/N interleaved in LDS (pn[2e]=P[e], pn[2e+1]=N[e]) so the 128-iter hot loop
// issues ONE ds_read_b64 + one b32 per step instead of three b32 (-33% LDS instr
// on the critical path). Staging stays all-b128/linear; sp/sn summation order
// unchanged. No contended atomics (R4-proven); one float2 partial per block.
__global__ __launch_bounds__(256) void local_dtw_kernel(
    const float* __restrict__ LF, const unsigned long long* __restrict__ posP,
    const unsigned long long* __restrict__ negP, float2* __restrict__ parts) {
  __shared__ float bufA[4][1024];
  __shared__ float bufPN[4][2048];
  __shared__ float dmP[4][64];
  __shared__ float dmN[4][64];
  __shared__ float gterms[4], lterms[4];
  const int w = threadIdx.x >> 6, lane = threadIdx.x & 63;
  const int a = blockIdx.x * 4 + w;
  const unsigned long long pp = posP[a];
  const unsigned long long nn = negP[a];
  const int p_ind = 4095 - (int)(pp & 0xFFFFFFFFULL);
  const int n_ind = (int)(nn & 0xFFFFFFFFULL);
  const float dist_ap = __uint_as_float((unsigned)(pp >> 32));
  const float dist_an = __uint_as_float((unsigned)(nn >> 32));

  const float4* ga = (const float4*)(LF + (size_t)a * 1024);
  const float4* gp = (const float4*)(LF + (size_t)p_ind * 1024);
  const float4* gn = (const float4*)(LF + (size_t)n_ind * 1024);
  float4* la = (float4*)bufA[w];
  float4* lpn = (float4*)bufPN[w];
#pragma unroll
  for (int i = 0; i < 4; ++i) {
    const int idx = lane + i * 64;
    la[idx] = ga[idx];
    float4 p = gp[idx];
    float4 n = gn[idx];
    // element e=idx*4+k of P goes to pn[2e], of N to pn[2e+1]
    lpn[2 * idx] = make_float4(p.x, n.x, p.y, n.y);
    lpn[2 * idx + 1] = make_float4(p.z, n.z, p.w, n.w);
  }
  __syncthreads();
  const int t1 = lane >> 3, t2 = lane & 7;
  float sp = 0.f, sn = 0.f;
#pragma unroll 8
  for (int d = 0; d < 128; ++d) {
    float xa = bufA[w][d * 8 + t1];
    float2 pnv = *(const float2*)&bufPN[w][2 * (d * 8 + t2)];
    float e1 = xa - pnv.x; sp += e1 * e1;
    float e2 = xa - pnv.y; sn += e2 * e2;
  }
  dmP[w][lane] = tanhf(0.5f * sqrtf(fmaxf(sp, 1e-12f)));  // == (e^d-1)/(e^d+1)
  dmN[w][lane] = tanhf(0.5f * sqrtf(fmaxf(sn, 1e-12f)));
  __syncthreads();
  // two serial 8x8 DPs per wave run concurrently on lanes 0 and 1
  if (lane < 2) {
    const float* dm = (lane == 0) ? dmP[w] : dmN[w];
    float row[8];
    row[0] = dm[0];
#pragma unroll
    for (int j = 1; j < 8; ++j) row[j] = row[j - 1] + dm[j];
#pragma unroll
    for (int i = 1; i < 8; ++i) {
      row[0] = row[0] + dm[i * 8];
#pragma unroll
      for (int j = 1; j < 8; ++j) row[j] = fminf(row[j], row[j - 1]) + dm[i * 8 + j];
    }
    if (lane == 0) dmP[w][0] = row[7];   // reuse LDS slot to pass ap
    else dmN[w][0] = row[7];             // an
  }
  __syncthreads();
  if (lane == 0) {
    gterms[w] = fmaxf(dist_ap - dist_an + MARGINF, 0.f);
    lterms[w] = fmaxf(dmP[w][0] - dmN[w][0] + MARGINF, 0.f);
  }
  __syncthreads();
  if (threadIdx.x == 0) {
    parts[blockIdx.x] = make_float2(gterms[0] + gterms[1] + gterms[2] + gterms[3],
                                    lterms[0] + lterms[1] + lterms[2] + lterms[3]);
  }
}

// ---------------- kernel 4: finalize — reduce 1024 partials, write out -------------
__global__ __launch_bounds__(256) void finalize_kernel(
    const float2* __restrict__ parts, float* __restrict__ out) {
  const int t = threadIdx.x;
  float g = 0.f, l = 0.f;
#pragma unroll
  for (int i = 0; i < 4; ++i) {
    float2 v = parts[t + i * 256];
    g += v.x; l += v.y;
  }
#pragma unroll
  for (int m = 32; m > 0; m >>= 1) {
    g += __shfl_down(g, m, 64);
    l += __shfl_down(l, m, 64);
  }
  __shared__ float sg[4], sl[4];
  if ((t & 63) == 0) { sg[t >> 6] = g; sl[t >> 6] = l; }
  __syncthreads();
  if (t == 0) {
    out[0] = (sg[0] + sg[1] + sg[2] + sg[3]) * (1.0f / 4096.0f);
    out[1] = (sl[0] + sl[1] + sl[2] + sl[3]) * (1.0f / 4096.0f);
  }
}

extern "C" void kernel_launch(void* const* d_in, const int* in_sizes, int n_in,
                              void* d_out, int out_size, void* d_ws, size_t ws_size,
                              hipStream_t stream) {
  const float* X = (const float*)d_in[0];
  const int* targets = (const int*)d_in[1];
  const float* LF = (const float*)d_in[2];
  float* out = (float*)d_out;

  char* ws = (char*)d_ws;
  size_t off = 0;
  unsigned short* Xbf = (unsigned short*)(ws + off); off += (size_t)NS * DIM * 2;  // 16 MB
  float* sq = (float*)(ws + off); off += (size_t)NS * 4;
  off = (off + 255) & ~(size_t)255;
  unsigned long long* posP = (unsigned long long*)(ws + off); off += (size_t)NS * 8;
  unsigned long long* negP = (unsigned long long*)(ws + off); off += (size_t)NS * 8;
  float2* parts = (float2*)(ws + off); off += (size_t)(NS / 4) * 8;

  prep_kernel<<<NS / 4, 256, 0, stream>>>(X, Xbf, sq, posP, negP);
  gemm_mine_kernel<<<NBLK, 128, 0, stream>>>(Xbf, sq, targets, posP, negP);
  local_dtw_kernel<<<NS / 4, 256, 0, stream>>>(LF, posP, negP, parts);
  finalize_kernel<<<1, 256, 0, stream>>>(parts, out);
}